// Round 1
// 260.762 us; speedup vs baseline: 1.0776x; 1.0776x over previous
//
#include <hip/hip_runtime.h>
#include <hip/hip_bf16.h>
#include <math.h>

constexpr int F = 128;        // in features
constexpr int H = 64;         // out features
constexpr int NB = 32;        // nodes per gemm block
constexpr int XS_STRIDE = F + 4;
constexpr int NXCD = 8;       // per-XCD privatized histogram copies

#define MASK40 ((1ull << 40) - 1)
#define Q24 16777216.0f

__device__ __forceinline__ float blo(unsigned u) { return __uint_as_float(u << 16); }
__device__ __forceinline__ float bhi(unsigned u) { return __uint_as_float(u & 0xffff0000u); }

// ---------------- init: pk = 0 (8 XCD-private copies) ----------------------
__global__ __launch_bounds__(256) void k_init(unsigned long long* __restrict__ pk,
                                              int n) {
  int i = blockIdx.x * 256 + threadIdx.x;
  if (i < n) pk[i] = 0ull;
}

// ------- one packed atomic per edge into the XCD-LOCAL copy ----------------
// Workgroup-scope atomic => RMW executes in this XCD's TCC (L2), not at the
// device-wide coherence point. Correct because copy r is only ever touched
// by blocks on XCD r (all sharing that L2).
__global__ __launch_bounds__(256) void k_count(const int* __restrict__ dst,
                                               const float* __restrict__ w,
                                               unsigned long long* __restrict__ pk,
                                               int* __restrict__ rank, int E, int N) {
  int e = blockIdx.x * 256 + threadIdx.x;
  if (e < E) {
    unsigned xcc;
    asm volatile("s_getreg_b32 %0, hwreg(HW_REG_XCC_ID)" : "=s"(xcc));
    xcc &= (NXCD - 1);
    int d = dst[e];
    unsigned long long enc =
        (1ull << 40) | (unsigned long long)__float2uint_rn(w[e] * Q24);
    unsigned long long old = __hip_atomic_fetch_add(
        &pk[(size_t)xcc * N + d], enc, __ATOMIC_RELAXED,
        __HIP_MEMORY_SCOPE_WORKGROUP);
    rank[e] = (int)(old >> 40) | ((int)xcc << 27);   // per-copy rank + copy id
  }
}

// ---- scan phase 1: fold 8 copies -> cnt/dinv/pre, block scan + block sum ----
__global__ __launch_bounds__(1024) void k_scan1(const unsigned long long* __restrict__ pk,
                                                int* __restrict__ cnt,
                                                float* __restrict__ dinv,
                                                int* __restrict__ cursor,
                                                int* __restrict__ bsum,
                                                int* __restrict__ pre, int N) {
  __shared__ int buf[1024];
  const int t = threadIdx.x;
  const int i = blockIdx.x * 1024 + t;
  int v = 0;
  if (i < N) {
    int run = 0;
    unsigned long long wsum = 0;
#pragma unroll
    for (int r = 0; r < NXCD; ++r) {
      unsigned long long p = pk[(size_t)r * N + i];
      pre[(size_t)r * N + i] = run;          // exclusive prefix across copies
      run += (int)(p >> 40);
      wsum += (p & MASK40);
    }
    v = run;
    cnt[i] = v;
    dinv[i] = rsqrtf(1.0f + (float)wsum * (1.0f / Q24));
  }
  buf[t] = v;
  __syncthreads();
  for (int off = 1; off < 1024; off <<= 1) {
    int add = (t >= off) ? buf[t - off] : 0;
    __syncthreads();
    buf[t] += add;
    __syncthreads();
  }
  if (i < N) cursor[i] = buf[t] - v;       // exclusive, block-local
  if (t == 1023) bsum[blockIdx.x] = buf[t];
}

// ---- scan phase 2+3: add prefix of block sums (<=49 blocks, inline loop) ----
__global__ __launch_bounds__(1024) void k_scan3(int* __restrict__ cursor,
                                                const int* __restrict__ bsum,
                                                int N) {
  __shared__ int off;
  if (threadIdx.x == 0) {
    int s = 0;
    for (int b = 0; b < (int)blockIdx.x; ++b) s += bsum[b];
    off = s;
  }
  __syncthreads();
  int i = blockIdx.x * 1024 + threadIdx.x;
  if (i < N) cursor[i] += off;
}

// ------- fill CSR, atomic-free: pos = cursor[d] + pre[r][d] + rank ----------
__global__ __launch_bounds__(256) void k_fill(const int* __restrict__ src,
                                              const int* __restrict__ dst,
                                              const float* __restrict__ w,
                                              const int* __restrict__ rank,
                                              const float* __restrict__ dinv,
                                              const int* __restrict__ cursor,
                                              const int* __restrict__ pre,
                                              int2* __restrict__ sorted, int E, int N) {
  int e = blockIdx.x * 256 + threadIdx.x;
  if (e < E) {
    int d = dst[e];
    int s = src[e];
    float sw = dinv[s] * w[e];
    int rr = rank[e];
    int r = ((unsigned)rr) >> 27;
    int rk = rr & ((1 << 27) - 1);
    int pos = cursor[d] + pre[(size_t)r * N + d] + rk;
    sorted[pos] = make_int2(s, __float_as_int(sw));
  }
}

// ---------------- h = x @ W, output bf16 (N x 128)@(128 x 64) ---------------
__global__ __launch_bounds__(256) void k_gemm(const float* __restrict__ x,
                                              const float* __restrict__ W,
                                              unsigned short* __restrict__ hb, int N) {
  __shared__ float Ws[F * H];
  __shared__ float xs[NB * XS_STRIDE];
  const int t = threadIdx.x;
  {
    const float4* W4 = (const float4*)W;
    float4* Ws4 = (float4*)Ws;
#pragma unroll
    for (int i = 0; i < (F * H / 4) / 256; ++i) Ws4[t + i * 256] = W4[t + i * 256];
  }
  const int node0 = blockIdx.x * NB;
  {
    const float4* x4 = (const float4*)(x + (size_t)node0 * F);
    int lim = (N - node0 < NB ? N - node0 : NB) * (F / 4);
    for (int i = t; i < NB * (F / 4); i += 256) {
      int nl = i / (F / 4), kk = i % (F / 4);
      float4 v = (i < lim) ? x4[i] : make_float4(0.f, 0.f, 0.f, 0.f);
      *(float4*)&xs[nl * XS_STRIDE + kk * 4] = v;
    }
  }
  __syncthreads();
  const int f0 = (t & 15) * 4;
  const int nl0 = (t >> 4) * 2;
  float acc[2][4] = {};
  for (int k = 0; k < F; k += 4) {
    float xr[2][4];
    float wr[4][4];
    *(float4*)&xr[0][0] = *(const float4*)&xs[(nl0 + 0) * XS_STRIDE + k];
    *(float4*)&xr[1][0] = *(const float4*)&xs[(nl0 + 1) * XS_STRIDE + k];
#pragma unroll
    for (int i = 0; i < 4; ++i)
      *(float4*)&wr[i][0] = *(const float4*)&Ws[(k + i) * H + f0];
#pragma unroll
    for (int i = 0; i < 4; ++i)
#pragma unroll
      for (int n = 0; n < 2; ++n)
#pragma unroll
        for (int j = 0; j < 4; ++j)
          acc[n][j] += xr[n][i] * wr[i][j];
  }
#pragma unroll
  for (int n = 0; n < 2; ++n) {
    int node = node0 + nl0 + n;
    if (node < N) {
      ushort4 o;
      o.x = __bfloat16_as_ushort(__float2bfloat16(acc[n][0]));
      o.y = __bfloat16_as_ushort(__float2bfloat16(acc[n][1]));
      o.z = __bfloat16_as_ushort(__float2bfloat16(acc[n][2]));
      o.w = __bfloat16_as_ushort(__float2bfloat16(acc[n][3]));
      *(ushort4*)&hb[(size_t)node * H + f0] = o;
    }
  }
}

// ---- gather-aggregate (bf16 h) + fused relu·dot: 16 lanes/node, 4 nodes/wave
__global__ __launch_bounds__(256) void k_agg(const int2* __restrict__ sorted,
                                             const int* __restrict__ cursor,
                                             const int* __restrict__ cnt,
                                             const float* __restrict__ dinv,
                                             const unsigned short* __restrict__ hb,
                                             const float* __restrict__ b,
                                             const float* __restrict__ fcw,
                                             float* __restrict__ partials, int N) {
  const int wid = threadIdx.x >> 6;
  const int lane = threadIdx.x & 63;
  const int seg = lane >> 4;        // 0..3: node segment within wave
  const int sl = lane & 15;         // lane within segment: 16 x 4 feats
  const int n = blockIdx.x * 16 + wid * 4 + seg;
  float p = 0.0f;
  if (n < N) {
    float dn = dinv[n];
    uint2 rn = *(const uint2*)(hb + ((size_t)n << 6) + (sl << 2));
    float4 bb = ((const float4*)b)[sl];
    float dn2 = dn * dn;
    float ax = bb.x + dn2 * blo(rn.x);
    float ay = bb.y + dn2 * bhi(rn.x);
    float az = bb.z + dn2 * blo(rn.y);
    float aw = bb.w + dn2 * bhi(rn.y);
    int e = cursor[n];
    int end = e + cnt[n];
    for (; e + 1 < end; e += 2) {
      int2 e0 = sorted[e];
      int2 e1 = sorted[e + 1];
      uint2 r0 = *(const uint2*)(hb + ((size_t)e0.x << 6) + (sl << 2));
      uint2 r1 = *(const uint2*)(hb + ((size_t)e1.x << 6) + (sl << 2));
      float n0 = dn * __int_as_float(e0.y);
      float n1 = dn * __int_as_float(e1.y);
      ax += n0 * blo(r0.x) + n1 * blo(r1.x);
      ay += n0 * bhi(r0.x) + n1 * bhi(r1.x);
      az += n0 * blo(r0.y) + n1 * blo(r1.y);
      aw += n0 * bhi(r0.y) + n1 * bhi(r1.y);
    }
    if (e < end) {
      int2 e0 = sorted[e];
      uint2 r0 = *(const uint2*)(hb + ((size_t)e0.x << 6) + (sl << 2));
      float n0 = dn * __int_as_float(e0.y);
      ax += n0 * blo(r0.x);
      ay += n0 * bhi(r0.x);
      az += n0 * blo(r0.y);
      aw += n0 * bhi(r0.y);
    }
    float4 fw = ((const float4*)fcw)[(size_t)n * 16 + sl];
    p = fmaxf(ax, 0.f) * fw.x + fmaxf(ay, 0.f) * fw.y +
        fmaxf(az, 0.f) * fw.z + fmaxf(aw, 0.f) * fw.w;
  }
  p += __shfl_down(p, 8);
  p += __shfl_down(p, 4);
  p += __shfl_down(p, 2);
  p += __shfl_down(p, 1);
  __shared__ float ls[16];
  if (sl == 0) ls[wid * 4 + seg] = p;
  __syncthreads();
  if (threadIdx.x == 0) {
    float s = 0.f;
#pragma unroll
    for (int i = 0; i < 16; ++i) s += ls[i];
    partials[blockIdx.x] = s;
  }
}

// ---------------- final: sum partials, + fc_b, sigmoid ----------------------
__global__ __launch_bounds__(1024) void k_fred(const float* __restrict__ partials,
                                               int M,
                                               const float* __restrict__ fcb,
                                               float* __restrict__ out) {
  const int t = threadIdx.x;
  float s = 0.0f;
  for (int i = t; i < M; i += 1024) s += partials[i];
#pragma unroll
  for (int off = 32; off > 0; off >>= 1) s += __shfl_down(s, off);
  __shared__ float ls[16];
  if ((t & 63) == 0) ls[t >> 6] = s;
  __syncthreads();
  if (t == 0) {
    float tot = 0.0f;
#pragma unroll
    for (int i = 0; i < 16; ++i) tot += ls[i];
    float logit = tot + fcb[0];
    out[0] = 1.0f / (1.0f + expf(-logit));
  }
}

extern "C" void kernel_launch(void* const* d_in, const int* in_sizes, int n_in,
                              void* d_out, int out_size, void* d_ws, size_t ws_size,
                              hipStream_t stream) {
  const float* x      = (const float*)d_in[0];
  const int*   elist  = (const int*)d_in[1];
  const float* eattr  = (const float*)d_in[2];
  const float* conv_w = (const float*)d_in[3];
  const float* conv_b = (const float*)d_in[4];
  const float* fc_w   = (const float*)d_in[5];
  const float* fc_b   = (const float*)d_in[6];
  float* out = (float*)d_out;

  const int N = in_sizes[0] / F;   // 50000
  const int E = in_sizes[2];       // 1,600,000
  const int* src = elist;
  const int* dst = elist + E;

  char* wsb = (char*)d_ws;
  int2*  sorted = (int2*)wsb;                                        // E*8 B
  unsigned long long* pk = (unsigned long long*)(wsb + (size_t)E * 8); // 8N*8 B
  int*   rank   = (int*)(pk + (size_t)NXCD * N);                     // E*4 B
  unsigned short* hb = (unsigned short*)(rank + E);                  // N*H*2 B
  int*   cnt    = (int*)(hb + (size_t)N * H);                        // N*4
  int*   cursor = cnt + N;                                           // N*4
  float* dinv   = (float*)(cursor + N);                              // N*4
  int*   pre    = (int*)(dinv + N);                                  // 8N*4
  float* partials = (float*)(pre + (size_t)NXCD * N);                // nAgg*4
  const int nAgg = (N + 15) / 16;
  int* bsum = (int*)(partials + nAgg);                               // nScan*4
  const int nScan = (N + 1023) / 1024;

  k_init<<<(NXCD * N + 255) / 256, 256, 0, stream>>>(pk, NXCD * N);
  k_count<<<(E + 255) / 256, 256, 0, stream>>>(dst, eattr, pk, rank, E, N);
  k_scan1<<<nScan, 1024, 0, stream>>>(pk, cnt, dinv, cursor, bsum, pre, N);
  k_scan3<<<nScan, 1024, 0, stream>>>(cursor, bsum, N);
  k_gemm<<<(N + NB - 1) / NB, 256, 0, stream>>>(x, conv_w, hb, N);
  k_fill<<<(E + 255) / 256, 256, 0, stream>>>(src, dst, eattr, rank, dinv, cursor,
                                              pre, sorted, E, N);
  k_agg<<<nAgg, 256, 0, stream>>>(sorted, cursor, cnt, dinv, hb, conv_b, fc_w,
                                  partials, N);
  k_fred<<<1, 1024, 0, stream>>>(partials, nAgg, fc_b, out);
}

// Round 2
// 253.777 us; speedup vs baseline: 1.1073x; 1.0275x over previous
//
#include <hip/hip_runtime.h>
#include <hip/hip_bf16.h>
#include <math.h>

constexpr int F = 128;        // in features
constexpr int H = 64;         // out features
constexpr int NB = 32;        // nodes per gemm block
constexpr int XS_STRIDE = F + 4;
constexpr int BCH = 64;       // edge chunks (histogram blocks per partition)
constexpr int PPART = 4;      // node partitions by low 2 bits of dst
constexpr int MAXBIN = 13000; // static LDS bins (>= ceil(N/4)), 52 KB

__device__ __forceinline__ float blo(unsigned u) { return __uint_as_float(u << 16); }
__device__ __forceinline__ float bhi(unsigned u) { return __uint_as_float(u & 0xffff0000u); }

// ---- histogram: LDS-private counts per (chunk b, partition p), local ranks --
// No global atomics anywhere: counts go to blk[p*BCH+b][bin], rank[e] is the
// LDS-atomic return (u16 safe: rank < chunk = 25000 < 65536).
__global__ __launch_bounds__(1024) void k_hist(const int* __restrict__ dst,
                                               int* __restrict__ blk,
                                               unsigned short* __restrict__ rank,
                                               int E, int chunk, int nbin) {
  __shared__ unsigned int lbin[MAXBIN];
  const int b = blockIdx.x;
  const int p = blockIdx.y;
  const int t = threadIdx.x;
  for (int i = t; i < nbin; i += 1024) lbin[i] = 0u;
  __syncthreads();
  const int e0 = b * chunk;
  const int e1 = min(e0 + chunk, E);
  for (int e = e0 + t; e < e1; e += 1024) {
    int d = dst[e];
    if ((d & (PPART - 1)) == p) {
      unsigned r = atomicAdd(&lbin[d >> 2], 1u);
      rank[e] = (unsigned short)r;
    }
  }
  __syncthreads();
  int* row = blk + (size_t)(p * BCH + b) * nbin;
  for (int i = t; i < nbin; i += 1024) row[i] = (int)lbin[i];
}

// ---- foldA: per-bin exclusive prefix within each octet of 8 chunks ---------
// (8-wide batched loads: enough MLP that the fold is BW-bound, not latency.)
__global__ __launch_bounds__(256) void k_foldA(int* __restrict__ blk,
                                               int* __restrict__ blkg,
                                               int N, int nbin) {
  const int i = blockIdx.x * 256 + threadIdx.x;
  const int g = blockIdx.y;          // octet 0..7
  if (i < N) {
    const int p = i & (PPART - 1);
    const int bl = i >> 2;
    size_t idx = (size_t)(p * BCH + g * 8) * nbin + bl;
    int vals[8];
#pragma unroll
    for (int u = 0; u < 8; ++u) vals[u] = blk[idx + (size_t)u * nbin];
    int s = 0;
#pragma unroll
    for (int u = 0; u < 8; ++u) {
      blk[idx + (size_t)u * nbin] = s;   // in-place exclusive prefix (octet)
      s += vals[u];
    }
    blkg[(size_t)g * N + i] = s;         // octet total
  }
}

// ---- scanB: fold 8 octet totals -> cnt, + block-level node scan ------------
__global__ __launch_bounds__(1024) void k_scanB(int* __restrict__ blkg,
                                                int* __restrict__ cnt,
                                                int* __restrict__ cursor,
                                                int* __restrict__ bsum, int N) {
  __shared__ int buf[1024];
  const int t = threadIdx.x;
  const int i = blockIdx.x * 1024 + t;
  int v = 0;
  if (i < N) {
    int og[8];
#pragma unroll
    for (int u = 0; u < 8; ++u) og[u] = blkg[(size_t)u * N + i];
    int s = 0;
#pragma unroll
    for (int u = 0; u < 8; ++u) {
      blkg[(size_t)u * N + i] = s;       // exclusive prefix across octets
      s += og[u];
    }
    v = s;
    cnt[i] = v;
  }
  buf[t] = v;
  __syncthreads();
  for (int off = 1; off < 1024; off <<= 1) {
    int add = (t >= off) ? buf[t - off] : 0;
    __syncthreads();
    buf[t] += add;
    __syncthreads();
  }
  if (i < N) cursor[i] = buf[t] - v;     // exclusive, block-local
  if (t == 1023) bsum[blockIdx.x] = buf[t];
}

// ---- scan phase 2+3: add prefix of block sums (<=49 blocks, inline loop) ----
__global__ __launch_bounds__(1024) void k_scan3(int* __restrict__ cursor,
                                                const int* __restrict__ bsum,
                                                int N) {
  __shared__ int off;
  if (threadIdx.x == 0) {
    int s = 0;
    for (int b = 0; b < (int)blockIdx.x; ++b) s += bsum[b];
    off = s;
  }
  __syncthreads();
  int i = blockIdx.x * 1024 + threadIdx.x;
  if (i < N) cursor[i] += off;
}

// ---- fill CSR, atomic-free: pos = cursor + octet base + chunk base + rank --
__global__ __launch_bounds__(256) void k_fill(const int* __restrict__ src,
                                              const int* __restrict__ dst,
                                              const float* __restrict__ w,
                                              const unsigned short* __restrict__ rank,
                                              const int* __restrict__ cursor,
                                              const int* __restrict__ blk,
                                              const int* __restrict__ blkg,
                                              int2* __restrict__ sorted,
                                              int E, int chunk, int nbin, int N) {
  int e = blockIdx.x * 256 + threadIdx.x;
  if (e < E) {
    int d = dst[e];
    int b = e / chunk;
    int p = d & (PPART - 1);
    int bl = d >> 2;
    int pos = cursor[d] + blkg[(size_t)(b >> 3) * N + d] +
              blk[(size_t)(p * BCH + b) * nbin + bl] + (int)rank[e];
    sorted[pos] = make_int2(src[e], __float_as_int(w[e]));  // raw w
  }
}

// ---- weighted degree from CSR (deterministic per-node order) -> dinv -------
__global__ __launch_bounds__(256) void k_deg(const int2* __restrict__ sorted,
                                             const int* __restrict__ cursor,
                                             const int* __restrict__ cnt,
                                             float* __restrict__ dinv, int N) {
  const int wid = threadIdx.x >> 6;
  const int lane = threadIdx.x & 63;
  const int seg = lane >> 4;
  const int sl = lane & 15;
  const int n = blockIdx.x * 16 + wid * 4 + seg;
  float s = 0.0f;
  if (n < N) {
    int e0 = cursor[n];
    int c = cnt[n];
    for (int j = sl; j < c; j += 16) s += __int_as_float(sorted[e0 + j].y);
  }
  s += __shfl_down(s, 8);
  s += __shfl_down(s, 4);
  s += __shfl_down(s, 2);
  s += __shfl_down(s, 1);
  if (n < N && sl == 0) dinv[n] = rsqrtf(1.0f + s);
}

// ---------------- h = x @ W, output bf16 (N x 128)@(128 x 64) ---------------
__global__ __launch_bounds__(256) void k_gemm(const float* __restrict__ x,
                                              const float* __restrict__ W,
                                              unsigned short* __restrict__ hb, int N) {
  __shared__ float Ws[F * H];
  __shared__ float xs[NB * XS_STRIDE];
  const int t = threadIdx.x;
  {
    const float4* W4 = (const float4*)W;
    float4* Ws4 = (float4*)Ws;
#pragma unroll
    for (int i = 0; i < (F * H / 4) / 256; ++i) Ws4[t + i * 256] = W4[t + i * 256];
  }
  const int node0 = blockIdx.x * NB;
  {
    const float4* x4 = (const float4*)(x + (size_t)node0 * F);
    int lim = (N - node0 < NB ? N - node0 : NB) * (F / 4);
    for (int i = t; i < NB * (F / 4); i += 256) {
      int nl = i / (F / 4), kk = i % (F / 4);
      float4 v = (i < lim) ? x4[i] : make_float4(0.f, 0.f, 0.f, 0.f);
      *(float4*)&xs[nl * XS_STRIDE + kk * 4] = v;
    }
  }
  __syncthreads();
  const int f0 = (t & 15) * 4;
  const int nl0 = (t >> 4) * 2;
  float acc[2][4] = {};
  for (int k = 0; k < F; k += 4) {
    float xr[2][4];
    float wr[4][4];
    *(float4*)&xr[0][0] = *(const float4*)&xs[(nl0 + 0) * XS_STRIDE + k];
    *(float4*)&xr[1][0] = *(const float4*)&xs[(nl0 + 1) * XS_STRIDE + k];
#pragma unroll
    for (int i = 0; i < 4; ++i)
      *(float4*)&wr[i][0] = *(const float4*)&Ws[(k + i) * H + f0];
#pragma unroll
    for (int i = 0; i < 4; ++i)
#pragma unroll
      for (int n = 0; n < 2; ++n)
#pragma unroll
        for (int j = 0; j < 4; ++j)
          acc[n][j] += xr[n][i] * wr[i][j];
  }
#pragma unroll
  for (int n = 0; n < 2; ++n) {
    int node = node0 + nl0 + n;
    if (node < N) {
      ushort4 o;
      o.x = __bfloat16_as_ushort(__float2bfloat16(acc[n][0]));
      o.y = __bfloat16_as_ushort(__float2bfloat16(acc[n][1]));
      o.z = __bfloat16_as_ushort(__float2bfloat16(acc[n][2]));
      o.w = __bfloat16_as_ushort(__float2bfloat16(acc[n][3]));
      *(ushort4*)&hb[(size_t)node * H + f0] = o;
    }
  }
}

// ---- gather-aggregate (bf16 h) + fused relu·dot: 16 lanes/node, 4 nodes/wave
__global__ __launch_bounds__(256) void k_agg(const int2* __restrict__ sorted,
                                             const int* __restrict__ cursor,
                                             const int* __restrict__ cnt,
                                             const float* __restrict__ dinv,
                                             const unsigned short* __restrict__ hb,
                                             const float* __restrict__ b,
                                             const float* __restrict__ fcw,
                                             float* __restrict__ partials, int N) {
  const int wid = threadIdx.x >> 6;
  const int lane = threadIdx.x & 63;
  const int seg = lane >> 4;        // 0..3: node segment within wave
  const int sl = lane & 15;         // lane within segment: 16 x 4 feats
  const int n = blockIdx.x * 16 + wid * 4 + seg;
  float p = 0.0f;
  if (n < N) {
    float dn = dinv[n];
    uint2 rn = *(const uint2*)(hb + ((size_t)n << 6) + (sl << 2));
    float4 bb = ((const float4*)b)[sl];
    float dn2 = dn * dn;
    float ax = bb.x + dn2 * blo(rn.x);
    float ay = bb.y + dn2 * bhi(rn.x);
    float az = bb.z + dn2 * blo(rn.y);
    float aw = bb.w + dn2 * bhi(rn.y);
    int e = cursor[n];
    int end = e + cnt[n];
    for (; e + 1 < end; e += 2) {
      int2 e0 = sorted[e];
      int2 e1 = sorted[e + 1];
      float dv0 = dinv[e0.x];
      float dv1 = dinv[e1.x];
      uint2 r0 = *(const uint2*)(hb + ((size_t)e0.x << 6) + (sl << 2));
      uint2 r1 = *(const uint2*)(hb + ((size_t)e1.x << 6) + (sl << 2));
      float n0 = dn * dv0 * __int_as_float(e0.y);
      float n1 = dn * dv1 * __int_as_float(e1.y);
      ax += n0 * blo(r0.x) + n1 * blo(r1.x);
      ay += n0 * bhi(r0.x) + n1 * bhi(r1.x);
      az += n0 * blo(r0.y) + n1 * blo(r1.y);
      aw += n0 * bhi(r0.y) + n1 * bhi(r1.y);
    }
    if (e < end) {
      int2 e0 = sorted[e];
      float dv0 = dinv[e0.x];
      uint2 r0 = *(const uint2*)(hb + ((size_t)e0.x << 6) + (sl << 2));
      float n0 = dn * dv0 * __int_as_float(e0.y);
      ax += n0 * blo(r0.x);
      ay += n0 * bhi(r0.x);
      az += n0 * blo(r0.y);
      aw += n0 * bhi(r0.y);
    }
    float4 fw = ((const float4*)fcw)[(size_t)n * 16 + sl];
    p = fmaxf(ax, 0.f) * fw.x + fmaxf(ay, 0.f) * fw.y +
        fmaxf(az, 0.f) * fw.z + fmaxf(aw, 0.f) * fw.w;
  }
  p += __shfl_down(p, 8);
  p += __shfl_down(p, 4);
  p += __shfl_down(p, 2);
  p += __shfl_down(p, 1);
  __shared__ float ls[16];
  if (sl == 0) ls[wid * 4 + seg] = p;
  __syncthreads();
  if (threadIdx.x == 0) {
    float s = 0.f;
#pragma unroll
    for (int i = 0; i < 16; ++i) s += ls[i];
    partials[blockIdx.x] = s;
  }
}

// ---------------- final: sum partials, + fc_b, sigmoid ----------------------
__global__ __launch_bounds__(1024) void k_fred(const float* __restrict__ partials,
                                               int M,
                                               const float* __restrict__ fcb,
                                               float* __restrict__ out) {
  const int t = threadIdx.x;
  float s = 0.0f;
  for (int i = t; i < M; i += 1024) s += partials[i];
#pragma unroll
  for (int off = 32; off > 0; off >>= 1) s += __shfl_down(s, off);
  __shared__ float ls[16];
  if ((t & 63) == 0) ls[t >> 6] = s;
  __syncthreads();
  if (t == 0) {
    float tot = 0.0f;
#pragma unroll
    for (int i = 0; i < 16; ++i) tot += ls[i];
    float logit = tot + fcb[0];
    out[0] = 1.0f / (1.0f + expf(-logit));
  }
}

extern "C" void kernel_launch(void* const* d_in, const int* in_sizes, int n_in,
                              void* d_out, int out_size, void* d_ws, size_t ws_size,
                              hipStream_t stream) {
  const float* x      = (const float*)d_in[0];
  const int*   elist  = (const int*)d_in[1];
  const float* eattr  = (const float*)d_in[2];
  const float* conv_w = (const float*)d_in[3];
  const float* conv_b = (const float*)d_in[4];
  const float* fc_w   = (const float*)d_in[5];
  const float* fc_b   = (const float*)d_in[6];
  float* out = (float*)d_out;

  const int N = in_sizes[0] / F;   // 50000
  const int E = in_sizes[2];       // 1,600,000
  const int* src = elist;
  const int* dst = elist + E;

  const int chunk = (E + BCH - 1) / BCH;       // 25000
  const int nbin  = (N + PPART - 1) / PPART;   // 12500 (<= MAXBIN)

  char* wsb = (char*)d_ws;
  int2* sorted = (int2*)wsb;                                   // E*8
  int*  blk    = (int*)(wsb + (size_t)E * 8);                  // P*BCH*nbin*4
  int*  blkg   = blk + (size_t)PPART * BCH * nbin;             // 8*N*4
  unsigned short* rank = (unsigned short*)(blkg + (size_t)8 * N);  // E*2
  unsigned short* hb   = rank + E;                             // N*H*2
  int*   cnt    = (int*)(hb + (size_t)N * H);                  // N*4
  int*   cursor = cnt + N;                                     // N*4
  float* dinv   = (float*)(cursor + N);                        // N*4
  float* partials = dinv + N;                                  // nAgg*4
  const int nAgg = (N + 15) / 16;
  int* bsum = (int*)(partials + nAgg);                         // nScan*4
  const int nScan = (N + 1023) / 1024;

  k_hist<<<dim3(BCH, PPART), 1024, 0, stream>>>(dst, blk, rank, E, chunk, nbin);
  k_foldA<<<dim3((N + 255) / 256, 8), 256, 0, stream>>>(blk, blkg, N, nbin);
  k_scanB<<<nScan, 1024, 0, stream>>>(blkg, cnt, cursor, bsum, N);
  k_scan3<<<nScan, 1024, 0, stream>>>(cursor, bsum, N);
  k_gemm<<<(N + NB - 1) / NB, 256, 0, stream>>>(x, conv_w, hb, N);
  k_fill<<<(E + 255) / 256, 256, 0, stream>>>(src, dst, eattr, rank, cursor, blk,
                                              blkg, sorted, E, chunk, nbin, N);
  k_deg<<<nAgg, 256, 0, stream>>>(sorted, cursor, cnt, dinv, N);
  k_agg<<<nAgg, 256, 0, stream>>>(sorted, cursor, cnt, dinv, hb, conv_b, fc_w,
                                  partials, N);
  k_fred<<<1, 1024, 0, stream>>>(partials, nAgg, fc_b, out);
}

// Round 3
// 248.885 us; speedup vs baseline: 1.1291x; 1.0197x over previous
//
#include <hip/hip_runtime.h>
#include <hip/hip_bf16.h>
#include <math.h>

constexpr int F = 128;        // in features
constexpr int H = 64;         // out features
constexpr int NB = 32;        // nodes per gemm block
constexpr int XS_STRIDE = F + 4;
constexpr int BCH = 64;       // edge chunks (histogram blocks per partition)
constexpr int PPART = 4;      // node partitions by low 2 bits of dst
constexpr int MAXBIN = 13000; // static LDS bins (>= ceil(N/4)), 52 KB

__device__ __forceinline__ float blo(unsigned u) { return __uint_as_float(u << 16); }
__device__ __forceinline__ float bhi(unsigned u) { return __uint_as_float(u & 0xffff0000u); }

// ---- histogram: LDS-private counts per (chunk b, partition p), local ranks --
// No global atomics anywhere: counts go to blk[p*BCH+b][bin], rank[e] is the
// LDS-atomic return (u16 safe: rank < chunk = 25000 < 65536).
__global__ __launch_bounds__(1024) void k_hist(const int* __restrict__ dst,
                                               int* __restrict__ blk,
                                               unsigned short* __restrict__ rank,
                                               int E, int chunk, int nbin) {
  __shared__ unsigned int lbin[MAXBIN];
  const int b = blockIdx.x;
  const int p = blockIdx.y;
  const int t = threadIdx.x;
  for (int i = t; i < nbin; i += 1024) lbin[i] = 0u;
  __syncthreads();
  const int e0 = b * chunk;
  const int e1 = min(e0 + chunk, E);
  for (int e = e0 + t; e < e1; e += 1024) {
    int d = dst[e];
    if ((d & (PPART - 1)) == p) {
      unsigned r = atomicAdd(&lbin[d >> 2], 1u);
      rank[e] = (unsigned short)r;
    }
  }
  __syncthreads();
  int* row = blk + (size_t)(p * BCH + b) * nbin;
  for (int i = t; i < nbin; i += 1024) row[i] = (int)lbin[i];
}

// ---- foldA: per-bin exclusive prefix within each octet of 8 chunks ---------
__global__ __launch_bounds__(256) void k_foldA(int* __restrict__ blk,
                                               int* __restrict__ blkg,
                                               int N, int nbin) {
  const int i = blockIdx.x * 256 + threadIdx.x;
  const int g = blockIdx.y;          // octet 0..7
  if (i < N) {
    const int p = i & (PPART - 1);
    const int bl = i >> 2;
    size_t idx = (size_t)(p * BCH + g * 8) * nbin + bl;
    int vals[8];
#pragma unroll
    for (int u = 0; u < 8; ++u) vals[u] = blk[idx + (size_t)u * nbin];
    int s = 0;
#pragma unroll
    for (int u = 0; u < 8; ++u) {
      blk[idx + (size_t)u * nbin] = s;   // in-place exclusive prefix (octet)
      s += vals[u];
    }
    blkg[(size_t)g * N + i] = s;         // octet total
  }
}

// ---- scanB: fold 8 octet totals -> cnt, + block-level node scan ------------
__global__ __launch_bounds__(1024) void k_scanB(int* __restrict__ blkg,
                                                int* __restrict__ cnt,
                                                int* __restrict__ cursor,
                                                int* __restrict__ bsum, int N) {
  __shared__ int buf[1024];
  const int t = threadIdx.x;
  const int i = blockIdx.x * 1024 + t;
  int v = 0;
  if (i < N) {
    int og[8];
#pragma unroll
    for (int u = 0; u < 8; ++u) og[u] = blkg[(size_t)u * N + i];
    int s = 0;
#pragma unroll
    for (int u = 0; u < 8; ++u) {
      blkg[(size_t)u * N + i] = s;       // exclusive prefix across octets
      s += og[u];
    }
    v = s;
    cnt[i] = v;
  }
  buf[t] = v;
  __syncthreads();
  for (int off = 1; off < 1024; off <<= 1) {
    int add = (t >= off) ? buf[t - off] : 0;
    __syncthreads();
    buf[t] += add;
    __syncthreads();
  }
  if (i < N) cursor[i] = buf[t] - v;     // exclusive, block-local
  if (t == 1023) bsum[blockIdx.x] = buf[t];
}

// ---- scan phase 2+3: add prefix of block sums (<=49 blocks, inline loop) ----
__global__ __launch_bounds__(1024) void k_scan3(int* __restrict__ cursor,
                                                const int* __restrict__ bsum,
                                                int N) {
  __shared__ int off;
  if (threadIdx.x == 0) {
    int s = 0;
    for (int b = 0; b < (int)blockIdx.x; ++b) s += bsum[b];
    off = s;
  }
  __syncthreads();
  int i = blockIdx.x * 1024 + threadIdx.x;
  if (i < N) cursor[i] += off;
}

// ---- fold2: blk[p,b][bl] += cursor + octet base  ->  ABSOLUTE position base
// Coalesced RMW of the 12.8 MB table; removes 2 of k_fill's 3 random gathers.
__global__ __launch_bounds__(256) void k_fold2(int* __restrict__ blk,
                                               const int* __restrict__ blkg,
                                               const int* __restrict__ cursor,
                                               int N, int nbin) {
  const int i = blockIdx.x * 256 + threadIdx.x;
  const int g = blockIdx.y;          // octet 0..7
  if (i < N) {
    int base = cursor[i] + blkg[(size_t)g * N + i];
    size_t idx = (size_t)((i & (PPART - 1)) * BCH + g * 8) * nbin + (i >> 2);
#pragma unroll
    for (int u = 0; u < 8; ++u) blk[idx + (size_t)u * nbin] += base;
  }
}

// ---- fill CSR: ONE base gather + nontemporal sector write ------------------
__global__ __launch_bounds__(256) void k_fill(const int* __restrict__ src,
                                              const int* __restrict__ dst,
                                              const float* __restrict__ w,
                                              const unsigned short* __restrict__ rank,
                                              const int* __restrict__ abase,
                                              unsigned long long* __restrict__ sorted,
                                              int E, int chunk, int nbin) {
  const int t0 = blockIdx.x * 1024 + threadIdx.x;
#pragma unroll
  for (int u = 0; u < 4; ++u) {
    int e = t0 + u * 256;
    if (e < E) {
      int d = dst[e];
      int b = e / chunk;
      int pos = abase[(size_t)((d & (PPART - 1)) * BCH + b) * nbin + (d >> 2)] +
                (int)rank[e];
      unsigned long long rec =
          ((unsigned long long)(unsigned)__float_as_int(w[e]) << 32) |
          (unsigned)src[e];
      __builtin_nontemporal_store(rec, &sorted[pos]);
    }
  }
}

// ---- weighted degree from CSR (deterministic per-node order) -> dinv -------
__global__ __launch_bounds__(256) void k_deg(const int2* __restrict__ sorted,
                                             const int* __restrict__ cursor,
                                             const int* __restrict__ cnt,
                                             float* __restrict__ dinv, int N) {
  const int wid = threadIdx.x >> 6;
  const int lane = threadIdx.x & 63;
  const int seg = lane >> 4;
  const int sl = lane & 15;
  const int n = blockIdx.x * 16 + wid * 4 + seg;
  float s = 0.0f;
  if (n < N) {
    int e0 = cursor[n];
    int c = cnt[n];
    for (int j = sl; j < c; j += 16) s += __int_as_float(sorted[e0 + j].y);
  }
  s += __shfl_down(s, 8);
  s += __shfl_down(s, 4);
  s += __shfl_down(s, 2);
  s += __shfl_down(s, 1);
  if (n < N && sl == 0) dinv[n] = rsqrtf(1.0f + s);
}

// ---------------- h = x @ W, output bf16 (N x 128)@(128 x 64) ---------------
__global__ __launch_bounds__(256) void k_gemm(const float* __restrict__ x,
                                              const float* __restrict__ W,
                                              unsigned short* __restrict__ hb, int N) {
  __shared__ float Ws[F * H];
  __shared__ float xs[NB * XS_STRIDE];
  const int t = threadIdx.x;
  {
    const float4* W4 = (const float4*)W;
    float4* Ws4 = (float4*)Ws;
#pragma unroll
    for (int i = 0; i < (F * H / 4) / 256; ++i) Ws4[t + i * 256] = W4[t + i * 256];
  }
  const int node0 = blockIdx.x * NB;
  {
    const float4* x4 = (const float4*)(x + (size_t)node0 * F);
    int lim = (N - node0 < NB ? N - node0 : NB) * (F / 4);
    for (int i = t; i < NB * (F / 4); i += 256) {
      int nl = i / (F / 4), kk = i % (F / 4);
      float4 v = (i < lim) ? x4[i] : make_float4(0.f, 0.f, 0.f, 0.f);
      *(float4*)&xs[nl * XS_STRIDE + kk * 4] = v;
    }
  }
  __syncthreads();
  const int f0 = (t & 15) * 4;
  const int nl0 = (t >> 4) * 2;
  float acc[2][4] = {};
  for (int k = 0; k < F; k += 4) {
    float xr[2][4];
    float wr[4][4];
    *(float4*)&xr[0][0] = *(const float4*)&xs[(nl0 + 0) * XS_STRIDE + k];
    *(float4*)&xr[1][0] = *(const float4*)&xs[(nl0 + 1) * XS_STRIDE + k];
#pragma unroll
    for (int i = 0; i < 4; ++i)
      *(float4*)&wr[i][0] = *(const float4*)&Ws[(k + i) * H + f0];
#pragma unroll
    for (int i = 0; i < 4; ++i)
#pragma unroll
      for (int n = 0; n < 2; ++n)
#pragma unroll
        for (int j = 0; j < 4; ++j)
          acc[n][j] += xr[n][i] * wr[i][j];
  }
#pragma unroll
  for (int n = 0; n < 2; ++n) {
    int node = node0 + nl0 + n;
    if (node < N) {
      ushort4 o;
      o.x = __bfloat16_as_ushort(__float2bfloat16(acc[n][0]));
      o.y = __bfloat16_as_ushort(__float2bfloat16(acc[n][1]));
      o.z = __bfloat16_as_ushort(__float2bfloat16(acc[n][2]));
      o.w = __bfloat16_as_ushort(__float2bfloat16(acc[n][3]));
      *(ushort4*)&hb[(size_t)node * H + f0] = o;
    }
  }
}

// ---- gather-aggregate (bf16 h) + fused relu·dot: 16 lanes/node, 4 nodes/wave
__global__ __launch_bounds__(256) void k_agg(const int2* __restrict__ sorted,
                                             const int* __restrict__ cursor,
                                             const int* __restrict__ cnt,
                                             const float* __restrict__ dinv,
                                             const unsigned short* __restrict__ hb,
                                             const float* __restrict__ b,
                                             const float* __restrict__ fcw,
                                             float* __restrict__ partials, int N) {
  const int wid = threadIdx.x >> 6;
  const int lane = threadIdx.x & 63;
  const int seg = lane >> 4;        // 0..3: node segment within wave
  const int sl = lane & 15;         // lane within segment: 16 x 4 feats
  const int n = blockIdx.x * 16 + wid * 4 + seg;
  float p = 0.0f;
  if (n < N) {
    float dn = dinv[n];
    uint2 rn = *(const uint2*)(hb + ((size_t)n << 6) + (sl << 2));
    float4 bb = ((const float4*)b)[sl];
    float dn2 = dn * dn;
    float ax = bb.x + dn2 * blo(rn.x);
    float ay = bb.y + dn2 * bhi(rn.x);
    float az = bb.z + dn2 * blo(rn.y);
    float aw = bb.w + dn2 * bhi(rn.y);
    int e = cursor[n];
    int end = e + cnt[n];
    for (; e + 1 < end; e += 2) {
      int2 e0 = sorted[e];
      int2 e1 = sorted[e + 1];
      float dv0 = dinv[e0.x];
      float dv1 = dinv[e1.x];
      uint2 r0 = *(const uint2*)(hb + ((size_t)e0.x << 6) + (sl << 2));
      uint2 r1 = *(const uint2*)(hb + ((size_t)e1.x << 6) + (sl << 2));
      float n0 = dn * dv0 * __int_as_float(e0.y);
      float n1 = dn * dv1 * __int_as_float(e1.y);
      ax += n0 * blo(r0.x) + n1 * blo(r1.x);
      ay += n0 * bhi(r0.x) + n1 * bhi(r1.x);
      az += n0 * blo(r0.y) + n1 * blo(r1.y);
      aw += n0 * bhi(r0.y) + n1 * bhi(r1.y);
    }
    if (e < end) {
      int2 e0 = sorted[e];
      float dv0 = dinv[e0.x];
      uint2 r0 = *(const uint2*)(hb + ((size_t)e0.x << 6) + (sl << 2));
      float n0 = dn * dv0 * __int_as_float(e0.y);
      ax += n0 * blo(r0.x);
      ay += n0 * bhi(r0.x);
      az += n0 * blo(r0.y);
      aw += n0 * bhi(r0.y);
    }
    float4 fw = ((const float4*)fcw)[(size_t)n * 16 + sl];
    p = fmaxf(ax, 0.f) * fw.x + fmaxf(ay, 0.f) * fw.y +
        fmaxf(az, 0.f) * fw.z + fmaxf(aw, 0.f) * fw.w;
  }
  p += __shfl_down(p, 8);
  p += __shfl_down(p, 4);
  p += __shfl_down(p, 2);
  p += __shfl_down(p, 1);
  __shared__ float ls[16];
  if (sl == 0) ls[wid * 4 + seg] = p;
  __syncthreads();
  if (threadIdx.x == 0) {
    float s = 0.f;
#pragma unroll
    for (int i = 0; i < 16; ++i) s += ls[i];
    partials[blockIdx.x] = s;
  }
}

// ---------------- final: sum partials, + fc_b, sigmoid ----------------------
__global__ __launch_bounds__(1024) void k_fred(const float* __restrict__ partials,
                                               int M,
                                               const float* __restrict__ fcb,
                                               float* __restrict__ out) {
  const int t = threadIdx.x;
  float s = 0.0f;
  for (int i = t; i < M; i += 1024) s += partials[i];
#pragma unroll
  for (int off = 32; off > 0; off >>= 1) s += __shfl_down(s, off);
  __shared__ float ls[16];
  if ((t & 63) == 0) ls[t >> 6] = s;
  __syncthreads();
  if (t == 0) {
    float tot = 0.0f;
#pragma unroll
    for (int i = 0; i < 16; ++i) tot += ls[i];
    float logit = tot + fcb[0];
    out[0] = 1.0f / (1.0f + expf(-logit));
  }
}

extern "C" void kernel_launch(void* const* d_in, const int* in_sizes, int n_in,
                              void* d_out, int out_size, void* d_ws, size_t ws_size,
                              hipStream_t stream) {
  const float* x      = (const float*)d_in[0];
  const int*   elist  = (const int*)d_in[1];
  const float* eattr  = (const float*)d_in[2];
  const float* conv_w = (const float*)d_in[3];
  const float* conv_b = (const float*)d_in[4];
  const float* fc_w   = (const float*)d_in[5];
  const float* fc_b   = (const float*)d_in[6];
  float* out = (float*)d_out;

  const int N = in_sizes[0] / F;   // 50000
  const int E = in_sizes[2];       // 1,600,000
  const int* src = elist;
  const int* dst = elist + E;

  const int chunk = (E + BCH - 1) / BCH;       // 25000
  const int nbin  = (N + PPART - 1) / PPART;   // 12500 (<= MAXBIN)

  char* wsb = (char*)d_ws;
  int2* sorted = (int2*)wsb;                                   // E*8
  int*  blk    = (int*)(wsb + (size_t)E * 8);                  // P*BCH*nbin*4
  int*  blkg   = blk + (size_t)PPART * BCH * nbin;             // 8*N*4
  unsigned short* rank = (unsigned short*)(blkg + (size_t)8 * N);  // E*2
  unsigned short* hb   = rank + E;                             // N*H*2
  int*   cnt    = (int*)(hb + (size_t)N * H);                  // N*4
  int*   cursor = cnt + N;                                     // N*4
  float* dinv   = (float*)(cursor + N);                        // N*4
  float* partials = dinv + N;                                  // nAgg*4
  const int nAgg = (N + 15) / 16;
  int* bsum = (int*)(partials + nAgg);                         // nScan*4
  const int nScan = (N + 1023) / 1024;

  k_hist<<<dim3(BCH, PPART), 1024, 0, stream>>>(dst, blk, rank, E, chunk, nbin);
  k_foldA<<<dim3((N + 255) / 256, 8), 256, 0, stream>>>(blk, blkg, N, nbin);
  k_scanB<<<nScan, 1024, 0, stream>>>(blkg, cnt, cursor, bsum, N);
  k_scan3<<<nScan, 1024, 0, stream>>>(cursor, bsum, N);
  k_fold2<<<dim3((N + 255) / 256, 8), 256, 0, stream>>>(blk, blkg, cursor, N, nbin);
  k_gemm<<<(N + NB - 1) / NB, 256, 0, stream>>>(x, conv_w, hb, N);
  k_fill<<<(E + 1023) / 1024, 256, 0, stream>>>(src, dst, eattr, rank, blk,
                                                (unsigned long long*)sorted, E,
                                                chunk, nbin);
  k_deg<<<nAgg, 256, 0, stream>>>(sorted, cursor, cnt, dinv, N);
  k_agg<<<nAgg, 256, 0, stream>>>(sorted, cursor, cnt, dinv, hb, conv_b, fc_w,
                                  partials, N);
  k_fred<<<1, 1024, 0, stream>>>(partials, nAgg, fc_b, out);
}